// Round 1
// baseline (748.747 us; speedup 1.0000x reference)
//
#include <hip/hip_runtime.h>

// GCN 2-layer: h = relu(gcnconv(x,W1,b1)); out = gcnconv(h,W2,b2)
// gcnconv: h=x@W; deg=1+indeg; dinv=rsqrt(deg); agg[dst]+=h[src]*dinv[src]*dinv[dst];
//          agg[i]+=h[i]*dinv[i]^2; return agg+b

#define N_NODES 100000
#define N_EDGES 1600000
// N_NODES % 16 == 0, % 32 == 0; N_EDGES*64 % 256 == 0 — exact grids, no tails.

__global__ __launch_bounds__(256) void k_init_deg(float* deg) {
    int i = blockIdx.x * 256 + threadIdx.x;
    if (i < N_NODES) deg[i] = 1.0f;   // self-loop
}

__global__ __launch_bounds__(256) void k_deg_scatter(const int* __restrict__ dst, float* deg) {
    int e = blockIdx.x * 256 + threadIdx.x;
    if (e < N_EDGES) atomicAdd(&deg[dst[e]], 1.0f);
}

__global__ __launch_bounds__(256) void k_rsqrt(float* deg) {
    int i = blockIdx.x * 256 + threadIdx.x;
    if (i < N_NODES) deg[i] = rsqrtf(deg[i]);   // in-place: deg -> dinv
}

// h1 = x @ W1 ; agg1 = h1*dinv[row]^2 + b1   (fused epilogue)
// block: 16 rows x 64 cols, 256 threads, thread = (row r=tid>>4, 4 cols cg=(tid&15)*4)
__global__ __launch_bounds__(256) void k_gemm1(const float* __restrict__ x,
                                               const float* __restrict__ W1,
                                               const float* __restrict__ b1,
                                               const float* __restrict__ dinv,
                                               float* __restrict__ h1,
                                               float* __restrict__ agg1) {
    __shared__ float Ws[128 * 64];      // 32 KB
    __shared__ float xs[16][132];       // +4 pad: banks (132r+k)%32 = (4r+k)%32, conflict-free
    int tid = threadIdx.x;
    for (int i = tid * 4; i < 128 * 64; i += 1024)
        *(float4*)&Ws[i] = *(const float4*)&W1[i];
    long rowBase = (long)blockIdx.x * 16;
    for (int i = tid; i < 512; i += 256) {          // 16 rows x 32 float4
        int r = i >> 5, c4 = i & 31;
        *(float4*)&xs[r][c4 * 4] = *(const float4*)&x[(rowBase + r) * 128 + c4 * 4];
    }
    __syncthreads();
    int r  = tid >> 4;
    int cg = (tid & 15) * 4;
    float a0 = 0, a1 = 0, a2 = 0, a3 = 0;
    #pragma unroll
    for (int k = 0; k < 128; ++k) {
        float xv = xs[r][k];
        const float* w = &Ws[k * 64 + cg];
        a0 = fmaf(xv, w[0], a0); a1 = fmaf(xv, w[1], a1);
        a2 = fmaf(xv, w[2], a2); a3 = fmaf(xv, w[3], a3);
    }
    long row = rowBase + r;
    *(float4*)&h1[row * 64 + cg] = (float4){a0, a1, a2, a3};
    float d  = dinv[row];
    float d2 = d * d;
    float4 bb = *(const float4*)&b1[cg];
    *(float4*)&agg1[row * 64 + cg] =
        (float4){fmaf(a0, d2, bb.x), fmaf(a1, d2, bb.y), fmaf(a2, d2, bb.z), fmaf(a3, d2, bb.w)};
}

// one wave per edge, lane = channel (64)
__global__ __launch_bounds__(256) void k_scatter1(const int* __restrict__ src,
                                                  const int* __restrict__ dst,
                                                  const float* __restrict__ dinv,
                                                  const float* __restrict__ h1,
                                                  float* agg1) {
    long gid = (long)blockIdx.x * 256 + threadIdx.x;
    int e = (int)(gid >> 6);
    int c = (int)(gid & 63);
    if (e >= N_EDGES) return;
    int s = src[e], d = dst[e];
    float w = dinv[s] * dinv[d];
    atomicAdd(&agg1[(long)d * 64 + c], h1[(long)s * 64 + c] * w);
}

// h2 = relu(agg1) @ W2 ; out = h2*dinv^2 + b2  (relu fused into LDS load; b1 already in agg1)
// block: 32 rows x 32 cols, 256 threads, thread = (r=tid>>3, cg=(tid&7)*4)
__global__ __launch_bounds__(256) void k_gemm2(const float* __restrict__ agg1,
                                               const float* __restrict__ W2,
                                               const float* __restrict__ b2,
                                               const float* __restrict__ dinv,
                                               float* __restrict__ h2,
                                               float* __restrict__ out) {
    __shared__ float Ws[64 * 32];       // 8 KB
    __shared__ float xs[32][68];        // +4 pad, conflict-free for r=tid>>3
    int tid = threadIdx.x;
    for (int i = tid * 4; i < 64 * 32; i += 1024)
        *(float4*)&Ws[i] = *(const float4*)&W2[i];
    long rowBase = (long)blockIdx.x * 32;
    for (int i = tid; i < 512; i += 256) {          // 32 rows x 16 float4
        int r = i >> 4, c4 = i & 15;
        float4 v = *(const float4*)&agg1[(rowBase + r) * 64 + c4 * 4];
        v.x = fmaxf(v.x, 0.f); v.y = fmaxf(v.y, 0.f);
        v.z = fmaxf(v.z, 0.f); v.w = fmaxf(v.w, 0.f);
        *(float4*)&xs[r][c4 * 4] = v;
    }
    __syncthreads();
    int r  = tid >> 3;
    int cg = (tid & 7) * 4;
    float a0 = 0, a1 = 0, a2 = 0, a3 = 0;
    #pragma unroll
    for (int k = 0; k < 64; ++k) {
        float xv = xs[r][k];
        const float* w = &Ws[k * 32 + cg];
        a0 = fmaf(xv, w[0], a0); a1 = fmaf(xv, w[1], a1);
        a2 = fmaf(xv, w[2], a2); a3 = fmaf(xv, w[3], a3);
    }
    long row = rowBase + r;
    *(float4*)&h2[row * 32 + cg] = (float4){a0, a1, a2, a3};
    float dv = dinv[row];
    float d2 = dv * dv;
    float4 bb = *(const float4*)&b2[cg];
    *(float4*)&out[row * 32 + cg] =
        (float4){fmaf(a0, d2, bb.x), fmaf(a1, d2, bb.y), fmaf(a2, d2, bb.z), fmaf(a3, d2, bb.w)};
}

// half-wave per edge, lane%32 = channel
__global__ __launch_bounds__(256) void k_scatter2(const int* __restrict__ src,
                                                  const int* __restrict__ dst,
                                                  const float* __restrict__ dinv,
                                                  const float* __restrict__ h2,
                                                  float* out) {
    long gid = (long)blockIdx.x * 256 + threadIdx.x;
    int e = (int)(gid >> 5);
    int c = (int)(gid & 31);
    if (e >= N_EDGES) return;
    int s = src[e], d = dst[e];
    float w = dinv[s] * dinv[d];
    atomicAdd(&out[(long)d * 32 + c], h2[(long)s * 32 + c] * w);
}

extern "C" void kernel_launch(void* const* d_in, const int* in_sizes, int n_in,
                              void* d_out, int out_size, void* d_ws, size_t ws_size,
                              hipStream_t stream) {
    const float* x  = (const float*)d_in[0];
    const int*   ei = (const int*)d_in[1];     // [2][N_EDGES]: row0=src, row1=dst
    const float* W1 = (const float*)d_in[2];
    const float* b1 = (const float*)d_in[3];
    const float* W2 = (const float*)d_in[4];
    const float* b2 = (const float*)d_in[5];
    float* out = (float*)d_out;

    const int* src = ei;
    const int* dst = ei + N_EDGES;

    // workspace layout (ws re-poisoned every call -> rebuild everything)
    char* ws = (char*)d_ws;
    float* dinv = (float*)ws;                                   // 400 KB slot
    float* h1   = (float*)(ws + (size_t)(1 << 19));             // 25.6 MB
    float* agg1 = (float*)(ws + (size_t)(1 << 19) + 26u * (1 << 20));   // 25.6 MB
    float* h2   = (float*)(ws + (size_t)(1 << 19) + 52u * (1 << 20));   // 12.8 MB
    // total ~65.3 MB

    k_init_deg   <<<(N_NODES + 255) / 256, 256, 0, stream>>>(dinv);
    k_deg_scatter<<<(N_EDGES + 255) / 256, 256, 0, stream>>>(dst, dinv);
    k_rsqrt      <<<(N_NODES + 255) / 256, 256, 0, stream>>>(dinv);
    k_gemm1      <<<N_NODES / 16, 256, 0, stream>>>(x, W1, b1, dinv, h1, agg1);
    k_scatter1   <<<(size_t)N_EDGES * 64 / 256, 256, 0, stream>>>(src, dst, dinv, h1, agg1);
    k_gemm2      <<<N_NODES / 32, 256, 0, stream>>>(agg1, W2, b2, dinv, h2, out);
    k_scatter2   <<<(size_t)N_EDGES * 32 / 256, 256, 0, stream>>>(src, dst, dinv, h2, out);
}

// Round 2
// 446.288 us; speedup vs baseline: 1.6777x; 1.6777x over previous
//
#include <hip/hip_runtime.h>

// GCN 2-layer via device-built CSR + gather (no feature-wide atomics).
// Layer: h = x@W; dinv = rsqrt(1+indeg); out[i] = dinv[i]*(sum_{s in in(i)} h[s]*dinv[s] + h[i]*dinv[i]) + b
// h1s/h2s hold the pre-scaled h*dinv rows; relu fused into gather1, final bias into gather2.

#define N_NODES 100000
#define N_EDGES 1600000
#define NB ((N_NODES + 1023) / 1024)   // 98 scan blocks

__global__ __launch_bounds__(256) void k_zero(int* udeg) {
    int i = blockIdx.x * 256 + threadIdx.x;
    if (i < N_NODES) udeg[i] = 0;
}

__global__ __launch_bounds__(256) void k_hist(const int* __restrict__ dst, int* udeg) {
    int e = blockIdx.x * 256 + threadIdx.x;
    if (e < N_EDGES) atomicAdd(&udeg[dst[e]], 1);
}

// Per-block (1024-elem) exclusive scan of udeg -> rowstart(local), block sums; also dinv.
__global__ __launch_bounds__(256) void k_scan_a(const int* __restrict__ udeg,
                                                float* __restrict__ dinv,
                                                int* __restrict__ rowstart,
                                                int* __restrict__ bsum) {
    __shared__ int s[256];
    int t = threadIdx.x;
    int base = blockIdx.x * 1024 + t * 4;
    int v0 = 0, v1 = 0, v2 = 0, v3 = 0;
    if (base + 0 < N_NODES) v0 = udeg[base + 0];
    if (base + 1 < N_NODES) v1 = udeg[base + 1];
    if (base + 2 < N_NODES) v2 = udeg[base + 2];
    if (base + 3 < N_NODES) v3 = udeg[base + 3];
    if (base + 0 < N_NODES) dinv[base + 0] = rsqrtf((float)(v0 + 1));
    if (base + 1 < N_NODES) dinv[base + 1] = rsqrtf((float)(v1 + 1));
    if (base + 2 < N_NODES) dinv[base + 2] = rsqrtf((float)(v2 + 1));
    if (base + 3 < N_NODES) dinv[base + 3] = rsqrtf((float)(v3 + 1));
    int tsum = v0 + v1 + v2 + v3;
    s[t] = tsum;
    __syncthreads();
    for (int off = 1; off < 256; off <<= 1) {
        int add = (t >= off) ? s[t - off] : 0;
        __syncthreads();
        s[t] += add;
        __syncthreads();
    }
    int excl = s[t] - tsum;
    if (t == 255) bsum[blockIdx.x] = s[t];
    if (base + 0 < N_NODES) rowstart[base + 0] = excl;
    if (base + 1 < N_NODES) rowstart[base + 1] = excl + v0;
    if (base + 2 < N_NODES) rowstart[base + 2] = excl + v0 + v1;
    if (base + 3 < N_NODES) rowstart[base + 3] = excl + v0 + v1 + v2;
}

__global__ __launch_bounds__(128) void k_scan_b(const int* __restrict__ bsum, int* __restrict__ boff) {
    __shared__ int s[128];
    int t = threadIdx.x;
    int v = (t < NB) ? bsum[t] : 0;
    s[t] = v;
    __syncthreads();
    for (int off = 1; off < 128; off <<= 1) {
        int add = (t >= off) ? s[t - off] : 0;
        __syncthreads();
        s[t] += add;
        __syncthreads();
    }
    if (t < NB) boff[t] = s[t] - v;
}

__global__ __launch_bounds__(256) void k_scan_c(int* rowstart, const int* __restrict__ boff, int* cursor) {
    int i = blockIdx.x * 256 + threadIdx.x;
    if (i < N_NODES) {
        int r = rowstart[i] + boff[i >> 10];
        rowstart[i] = r;
        cursor[i]   = r;
    }
}

__global__ __launch_bounds__(256) void k_build(const int* __restrict__ src, const int* __restrict__ dst,
                                               int* cursor, int* __restrict__ csr) {
    int e = blockIdx.x * 256 + threadIdx.x;
    if (e < N_EDGES) {
        int pos = atomicAdd(&cursor[dst[e]], 1);
        csr[pos] = src[e];
    }
}

// h1s = (x @ W1) * dinv[row]
// block: 16 rows x 64 cols, 256 threads, thread = (r=tid>>4, cg=(tid&15)*4)
__global__ __launch_bounds__(256) void k_gemm1(const float* __restrict__ x,
                                               const float* __restrict__ W1,
                                               const float* __restrict__ dinv,
                                               float* __restrict__ h1s) {
    __shared__ float Ws[128 * 64];      // 32 KB
    __shared__ float xs[16][132];       // +4 pad, conflict-free
    int tid = threadIdx.x;
    for (int i = tid * 4; i < 128 * 64; i += 1024)
        *(float4*)&Ws[i] = *(const float4*)&W1[i];
    long rowBase = (long)blockIdx.x * 16;
    for (int i = tid; i < 512; i += 256) {          // 16 rows x 32 float4
        int r = i >> 5, c4 = i & 31;
        *(float4*)&xs[r][c4 * 4] = *(const float4*)&x[(rowBase + r) * 128 + c4 * 4];
    }
    __syncthreads();
    int r  = tid >> 4;
    int cg = (tid & 15) * 4;
    float a0 = 0, a1 = 0, a2 = 0, a3 = 0;
    #pragma unroll
    for (int k = 0; k < 128; ++k) {
        float xv = xs[r][k];
        const float* w = &Ws[k * 64 + cg];
        a0 = fmaf(xv, w[0], a0); a1 = fmaf(xv, w[1], a1);
        a2 = fmaf(xv, w[2], a2); a3 = fmaf(xv, w[3], a3);
    }
    long row = rowBase + r;
    float dv = dinv[row];
    *(float4*)&h1s[row * 64 + cg] = (float4){a0 * dv, a1 * dv, a2 * dv, a3 * dv};
}

// g1[i] = relu(dinv[i]*(sum_{s} h1s[s] + h1s[i]) + b1)   — wave per node, lane=channel
__global__ __launch_bounds__(256) void k_gather1(const int* __restrict__ rowstart,
                                                 const int* __restrict__ udeg,
                                                 const int* __restrict__ csr,
                                                 const float* __restrict__ dinv,
                                                 const float* __restrict__ h1s,
                                                 const float* __restrict__ b1,
                                                 float* __restrict__ g1) {
    long gid = (long)blockIdx.x * 256 + threadIdx.x;
    int i = (int)(gid >> 6);
    int c = (int)(gid & 63);
    int n = udeg[i];
    int base = rowstart[i];
    float sum = h1s[(long)i * 64 + c];
    int k = 0;
    for (; k + 4 <= n; k += 4) {
        int s0 = csr[base + k], s1 = csr[base + k + 1], s2 = csr[base + k + 2], s3 = csr[base + k + 3];
        float f0 = h1s[(long)s0 * 64 + c], f1 = h1s[(long)s1 * 64 + c];
        float f2 = h1s[(long)s2 * 64 + c], f3 = h1s[(long)s3 * 64 + c];
        sum += (f0 + f1) + (f2 + f3);
    }
    for (; k < n; ++k) sum += h1s[(long)csr[base + k] * 64 + c];
    float r = fmaf(dinv[i], sum, b1[c]);
    g1[(long)i * 64 + c] = fmaxf(r, 0.0f);
}

// h2s = (g1 @ W2) * dinv[row]
// block: 32 rows x 32 cols, 256 threads, thread = (r=tid>>3, cg=(tid&7)*4)
__global__ __launch_bounds__(256) void k_gemm2(const float* __restrict__ g1,
                                               const float* __restrict__ W2,
                                               const float* __restrict__ dinv,
                                               float* __restrict__ h2s) {
    __shared__ float Ws[64 * 32];       // 8 KB
    __shared__ float xs[32][68];        // +4 pad
    int tid = threadIdx.x;
    for (int i = tid * 4; i < 64 * 32; i += 1024)
        *(float4*)&Ws[i] = *(const float4*)&W2[i];
    long rowBase = (long)blockIdx.x * 32;
    for (int i = tid; i < 512; i += 256) {          // 32 rows x 16 float4
        int r = i >> 4, c4 = i & 15;
        *(float4*)&xs[r][c4 * 4] = *(const float4*)&g1[(rowBase + r) * 64 + c4 * 4];
    }
    __syncthreads();
    int r  = tid >> 3;
    int cg = (tid & 7) * 4;
    float a0 = 0, a1 = 0, a2 = 0, a3 = 0;
    #pragma unroll
    for (int k = 0; k < 64; ++k) {
        float xv = xs[r][k];
        const float* w = &Ws[k * 32 + cg];
        a0 = fmaf(xv, w[0], a0); a1 = fmaf(xv, w[1], a1);
        a2 = fmaf(xv, w[2], a2); a3 = fmaf(xv, w[3], a3);
    }
    long row = rowBase + r;
    float dv = dinv[row];
    *(float4*)&h2s[row * 32 + cg] = (float4){a0 * dv, a1 * dv, a2 * dv, a3 * dv};
}

// out[i] = dinv[i]*(sum_{s} h2s[s] + h2s[i]) + b2   — half-wave per node, 32 ch
__global__ __launch_bounds__(256) void k_gather2(const int* __restrict__ rowstart,
                                                 const int* __restrict__ udeg,
                                                 const int* __restrict__ csr,
                                                 const float* __restrict__ dinv,
                                                 const float* __restrict__ h2s,
                                                 const float* __restrict__ b2,
                                                 float* __restrict__ out) {
    long gid = (long)blockIdx.x * 256 + threadIdx.x;
    int i = (int)(gid >> 5);
    int c = (int)(gid & 31);
    int n = udeg[i];
    int base = rowstart[i];
    float sum = h2s[(long)i * 32 + c];
    int k = 0;
    for (; k + 4 <= n; k += 4) {
        int s0 = csr[base + k], s1 = csr[base + k + 1], s2 = csr[base + k + 2], s3 = csr[base + k + 3];
        float f0 = h2s[(long)s0 * 32 + c], f1 = h2s[(long)s1 * 32 + c];
        float f2 = h2s[(long)s2 * 32 + c], f3 = h2s[(long)s3 * 32 + c];
        sum += (f0 + f1) + (f2 + f3);
    }
    for (; k < n; ++k) sum += h2s[(long)csr[base + k] * 32 + c];
    out[(long)i * 32 + c] = fmaf(dinv[i], sum, b2[c]);
}

extern "C" void kernel_launch(void* const* d_in, const int* in_sizes, int n_in,
                              void* d_out, int out_size, void* d_ws, size_t ws_size,
                              hipStream_t stream) {
    const float* x  = (const float*)d_in[0];
    const int*   ei = (const int*)d_in[1];     // [2][N_EDGES]: row0=src, row1=dst
    const float* W1 = (const float*)d_in[2];
    const float* b1 = (const float*)d_in[3];
    const float* W2 = (const float*)d_in[4];
    const float* b2 = (const float*)d_in[5];
    float* out = (float*)d_out;

    const int* src = ei;
    const int* dst = ei + N_EDGES;

    char* ws = (char*)d_ws;
    const size_t MB = 1u << 20;
    int*   udeg     = (int*)  (ws + 0);                 // 400 KB
    float* dinv     = (float*)(ws + 512 * 1024);        // 400 KB
    int*   rowstart = (int*)  (ws + 1 * MB);            // 400 KB
    int*   cursor   = (int*)  (ws + 1 * MB + 512 * 1024);
    int*   bsum     = (int*)  (ws + 2 * MB);            // 98 ints
    int*   boff     = (int*)  (ws + 2 * MB + 64 * 1024);
    int*   csr      = (int*)  (ws + 3 * MB);            // 6.4 MB
    float* h1s      = (float*)(ws + 10 * MB);           // 25.6 MB
    float* g1       = (float*)(ws + 36 * MB);           // 25.6 MB
    float* h2s      = (float*)(ws + 62 * MB);           // 12.8 MB (ends ~74.8 MB)

    k_zero   <<<(N_NODES + 255) / 256, 256, 0, stream>>>(udeg);
    k_hist   <<<(N_EDGES + 255) / 256, 256, 0, stream>>>(dst, udeg);
    k_scan_a <<<NB, 256, 0, stream>>>(udeg, dinv, rowstart, bsum);
    k_scan_b <<<1, 128, 0, stream>>>(bsum, boff);
    k_scan_c <<<(N_NODES + 255) / 256, 256, 0, stream>>>(rowstart, boff, cursor);
    k_build  <<<(N_EDGES + 255) / 256, 256, 0, stream>>>(src, dst, cursor, csr);
    k_gemm1  <<<N_NODES / 16, 256, 0, stream>>>(x, W1, dinv, h1s);
    k_gather1<<<(size_t)N_NODES * 64 / 256, 256, 0, stream>>>(rowstart, udeg, csr, dinv, h1s, b1, g1);
    k_gemm2  <<<N_NODES / 32, 256, 0, stream>>>(g1, W2, dinv, h2s);
    k_gather2<<<(size_t)N_NODES * 32 / 256, 256, 0, stream>>>(rowstart, udeg, csr, dinv, h2s, b2, out);
}

// Round 4
// 389.002 us; speedup vs baseline: 1.9248x; 1.1473x over previous
//
#include <hip/hip_runtime.h>

// GCN 2-layer via device-built CSR + gather.
// CSR build = two-level counting sort: bucket (dst>>8) binning pass, then
// per-bucket scatter into an L2-resident csr window (merged writebacks).

#define N_NODES 100000
#define N_EDGES 1600000
#define NB ((N_NODES + 1023) / 1024)   // 98 scan blocks
#define BSHIFT 8
#define NBUCK ((N_NODES + 255) / 256)  // 391

__global__ __launch_bounds__(256) void k_zero(int* udeg) {
    int i = blockIdx.x * 256 + threadIdx.x;
    if (i < N_NODES) udeg[i] = 0;
}

__global__ __launch_bounds__(256) void k_hist(const int* __restrict__ dst, int* udeg) {
    int e = blockIdx.x * 256 + threadIdx.x;
    if (e < N_EDGES) atomicAdd(&udeg[dst[e]], 1);
}

// Per-block (1024-elem) exclusive scan of udeg -> rowstart(local), block sums; also dinv.
__global__ __launch_bounds__(256) void k_scan_a(const int* __restrict__ udeg,
                                                float* __restrict__ dinv,
                                                int* __restrict__ rowstart,
                                                int* __restrict__ bsum) {
    __shared__ int s[256];
    int t = threadIdx.x;
    int base = blockIdx.x * 1024 + t * 4;
    int v0 = 0, v1 = 0, v2 = 0, v3 = 0;
    if (base + 0 < N_NODES) v0 = udeg[base + 0];
    if (base + 1 < N_NODES) v1 = udeg[base + 1];
    if (base + 2 < N_NODES) v2 = udeg[base + 2];
    if (base + 3 < N_NODES) v3 = udeg[base + 3];
    if (base + 0 < N_NODES) dinv[base + 0] = rsqrtf((float)(v0 + 1));
    if (base + 1 < N_NODES) dinv[base + 1] = rsqrtf((float)(v1 + 1));
    if (base + 2 < N_NODES) dinv[base + 2] = rsqrtf((float)(v2 + 1));
    if (base + 3 < N_NODES) dinv[base + 3] = rsqrtf((float)(v3 + 1));
    int tsum = v0 + v1 + v2 + v3;
    s[t] = tsum;
    __syncthreads();
    for (int off = 1; off < 256; off <<= 1) {
        int add = (t >= off) ? s[t - off] : 0;
        __syncthreads();
        s[t] += add;
        __syncthreads();
    }
    int excl = s[t] - tsum;
    if (t == 255) bsum[blockIdx.x] = s[t];
    if (base + 0 < N_NODES) rowstart[base + 0] = excl;
    if (base + 1 < N_NODES) rowstart[base + 1] = excl + v0;
    if (base + 2 < N_NODES) rowstart[base + 2] = excl + v0 + v1;
    if (base + 3 < N_NODES) rowstart[base + 3] = excl + v0 + v1 + v2;
}

__global__ __launch_bounds__(128) void k_scan_b(const int* __restrict__ bsum, int* __restrict__ boff) {
    __shared__ int s[128];
    int t = threadIdx.x;
    int v = (t < NB) ? bsum[t] : 0;
    s[t] = v;
    __syncthreads();
    for (int off = 1; off < 128; off <<= 1) {
        int add = (t >= off) ? s[t - off] : 0;
        __syncthreads();
        s[t] += add;
        __syncthreads();
    }
    if (t < NB) boff[t] = s[t] - v;
}

__global__ __launch_bounds__(256) void k_scan_c(int* rowstart, const int* __restrict__ boff, int* cursor) {
    int i = blockIdx.x * 256 + threadIdx.x;
    if (i < N_NODES) {
        int r = rowstart[i] + boff[i >> 10];
        rowstart[i] = r;
        cursor[i]   = r;
    }
}

// bucket write cursors = rowstart at bucket boundaries
__global__ __launch_bounds__(256) void k_binit(const int* __restrict__ rowstart, int* gcursor) {
    int b = blockIdx.x * 256 + threadIdx.x;
    if (b < NBUCK) {
        int node = b << BSHIFT;
        gcursor[b] = (node < N_NODES) ? rowstart[node] : N_EDGES;
    }
}

// Pass A: bin (dst,src) pairs into NBUCK coarse-bucket regions of tmp.
// Per block: LDS count -> one global reserve per nonempty bucket -> ranked scatter.
__global__ __launch_bounds__(256) void k_bucketA(const int* __restrict__ src,
                                                 const int* __restrict__ dst,
                                                 int* gcursor, int2* __restrict__ tmp) {
    __shared__ int lcnt[NBUCK];
    __shared__ int lpos[NBUCK];
    int t = threadIdx.x;
    for (int b = t; b < NBUCK; b += 256) lcnt[b] = 0;
    __syncthreads();
    long e0 = (long)blockIdx.x * 4096;
    for (int k = 0; k < 16; ++k) {
        long e = e0 + k * 256 + t;
        if (e < N_EDGES) atomicAdd(&lcnt[dst[e] >> BSHIFT], 1);
    }
    __syncthreads();
    for (int b = t; b < NBUCK; b += 256) {
        int c = lcnt[b];
        lpos[b] = c ? atomicAdd(&gcursor[b], c) : 0;
    }
    __syncthreads();
    for (int k = 0; k < 16; ++k) {
        long e = e0 + k * 256 + t;
        if (e < N_EDGES) {
            int d = dst[e];
            int p = atomicAdd(&lpos[d >> BSHIFT], 1);
            tmp[p] = (int2){d, src[e]};
        }
    }
}

// Pass B: one block per bucket; scatter bucket's pairs into its ~16KB csr
// window via per-node cursor atomics. Reads & writes stay L2-resident.
__global__ __launch_bounds__(256) void k_bucketB(const int* __restrict__ rowstart,
                                                 const int2* __restrict__ tmp,
                                                 int* cursor, int* __restrict__ csr) {
    int b  = blockIdx.x;
    int n0 = b << BSHIFT;
    int n1 = n0 + (1 << BSHIFT);
    int start = rowstart[n0];
    int end   = (n1 < N_NODES) ? rowstart[n1] : N_EDGES;
    for (int e = start + (int)threadIdx.x; e < end; e += 256) {
        int2 p = tmp[e];
        int pos = atomicAdd(&cursor[p.x], 1);
        csr[pos] = p.y;
    }
}

// h1s = (x @ W1) * dinv[row]
__global__ __launch_bounds__(256) void k_gemm1(const float* __restrict__ x,
                                               const float* __restrict__ W1,
                                               const float* __restrict__ dinv,
                                               float* __restrict__ h1s) {
    __shared__ float Ws[128 * 64];      // 32 KB
    __shared__ float xs[16][132];       // +4 pad, conflict-free
    int tid = threadIdx.x;
    for (int i = tid * 4; i < 128 * 64; i += 1024)
        *(float4*)&Ws[i] = *(const float4*)&W1[i];
    long rowBase = (long)blockIdx.x * 16;
    for (int i = tid; i < 512; i += 256) {
        int r = i >> 5, c4 = i & 31;
        *(float4*)&xs[r][c4 * 4] = *(const float4*)&x[(rowBase + r) * 128 + c4 * 4];
    }
    __syncthreads();
    int r  = tid >> 4;
    int cg = (tid & 15) * 4;
    float a0 = 0, a1 = 0, a2 = 0, a3 = 0;
    #pragma unroll
    for (int k = 0; k < 128; ++k) {
        float xv = xs[r][k];
        const float* w = &Ws[k * 64 + cg];
        a0 = fmaf(xv, w[0], a0); a1 = fmaf(xv, w[1], a1);
        a2 = fmaf(xv, w[2], a2); a3 = fmaf(xv, w[3], a3);
    }
    long row = rowBase + r;
    float dv = dinv[row];
    *(float4*)&h1s[row * 64 + cg] = (float4){a0 * dv, a1 * dv, a2 * dv, a3 * dv};
}

// g1[i] = relu(dinv[i]*(sum_s h1s[s] + h1s[i]) + b1)  — wave per node, lane=channel
__global__ __launch_bounds__(256) void k_gather1(const int* __restrict__ rowstart,
                                                 const int* __restrict__ udeg,
                                                 const int* __restrict__ csr,
                                                 const float* __restrict__ dinv,
                                                 const float* __restrict__ h1s,
                                                 const float* __restrict__ b1,
                                                 float* __restrict__ g1) {
    long gid = (long)blockIdx.x * 256 + threadIdx.x;
    int i = (int)(gid >> 6);
    int c = (int)(gid & 63);
    int n = udeg[i];
    int base = rowstart[i];
    float sum = h1s[(long)i * 64 + c];
    int k = 0;
    for (; k + 4 <= n; k += 4) {
        int s0 = csr[base + k], s1 = csr[base + k + 1], s2 = csr[base + k + 2], s3 = csr[base + k + 3];
        float f0 = h1s[(long)s0 * 64 + c], f1 = h1s[(long)s1 * 64 + c];
        float f2 = h1s[(long)s2 * 64 + c], f3 = h1s[(long)s3 * 64 + c];
        sum += (f0 + f1) + (f2 + f3);
    }
    for (; k < n; ++k) sum += h1s[(long)csr[base + k] * 64 + c];
    float r = fmaf(dinv[i], sum, b1[c]);
    g1[(long)i * 64 + c] = fmaxf(r, 0.0f);
}

// h2s = (g1 @ W2) * dinv[row]
__global__ __launch_bounds__(256) void k_gemm2(const float* __restrict__ g1,
                                               const float* __restrict__ W2,
                                               const float* __restrict__ dinv,
                                               float* __restrict__ h2s) {
    __shared__ float Ws[64 * 32];       // 8 KB
    __shared__ float xs[32][68];        // +4 pad
    int tid = threadIdx.x;
    for (int i = tid * 4; i < 64 * 32; i += 1024)
        *(float4*)&Ws[i] = *(const float4*)&W2[i];
    long rowBase = (long)blockIdx.x * 32;
    for (int i = tid; i < 512; i += 256) {
        int r = i >> 4, c4 = i & 15;
        *(float4*)&xs[r][c4 * 4] = *(const float4*)&g1[(rowBase + r) * 64 + c4 * 4];
    }
    __syncthreads();
    int r  = tid >> 3;
    int cg = (tid & 7) * 4;
    float a0 = 0, a1 = 0, a2 = 0, a3 = 0;
    #pragma unroll
    for (int k = 0; k < 64; ++k) {
        float xv = xs[r][k];
        const float* w = &Ws[k * 32 + cg];
        a0 = fmaf(xv, w[0], a0); a1 = fmaf(xv, w[1], a1);
        a2 = fmaf(xv, w[2], a2); a3 = fmaf(xv, w[3], a3);
    }
    long row = rowBase + r;
    float dv = dinv[row];
    *(float4*)&h2s[row * 32 + cg] = (float4){a0 * dv, a1 * dv, a2 * dv, a3 * dv};
}

// out[i] = dinv[i]*(sum_s h2s[s] + h2s[i]) + b2  — half-wave per node, 32 ch
__global__ __launch_bounds__(256) void k_gather2(const int* __restrict__ rowstart,
                                                 const int* __restrict__ udeg,
                                                 const int* __restrict__ csr,
                                                 const float* __restrict__ dinv,
                                                 const float* __restrict__ h2s,
                                                 const float* __restrict__ b2,
                                                 float* __restrict__ out) {
    long gid = (long)blockIdx.x * 256 + threadIdx.x;
    int i = (int)(gid >> 5);
    int c = (int)(gid & 31);
    int n = udeg[i];
    int base = rowstart[i];
    float sum = h2s[(long)i * 32 + c];
    int k = 0;
    for (; k + 4 <= n; k += 4) {
        int s0 = csr[base + k], s1 = csr[base + k + 1], s2 = csr[base + k + 2], s3 = csr[base + k + 3];
        float f0 = h2s[(long)s0 * 32 + c], f1 = h2s[(long)s1 * 32 + c];
        float f2 = h2s[(long)s2 * 32 + c], f3 = h2s[(long)s3 * 32 + c];
        sum += (f0 + f1) + (f2 + f3);
    }
    for (; k < n; ++k) sum += h2s[(long)csr[base + k] * 32 + c];
    out[(long)i * 32 + c] = fmaf(dinv[i], sum, b2[c]);
}

extern "C" void kernel_launch(void* const* d_in, const int* in_sizes, int n_in,
                              void* d_out, int out_size, void* d_ws, size_t ws_size,
                              hipStream_t stream) {
    const float* x  = (const float*)d_in[0];
    const int*   ei = (const int*)d_in[1];     // [2][N_EDGES]: row0=src, row1=dst
    const float* W1 = (const float*)d_in[2];
    const float* b1 = (const float*)d_in[3];
    const float* W2 = (const float*)d_in[4];
    const float* b2 = (const float*)d_in[5];
    float* out = (float*)d_out;

    const int* src = ei;
    const int* dst = ei + N_EDGES;

    char* ws = (char*)d_ws;
    const size_t MB = 1u << 20;
    int*   udeg     = (int*)  (ws + 0);                 // 400 KB
    float* dinv     = (float*)(ws + 512 * 1024);        // 400 KB
    int*   rowstart = (int*)  (ws + 1 * MB);            // 400 KB
    int*   cursor   = (int*)  (ws + 1 * MB + 512 * 1024);
    int*   bsum     = (int*)  (ws + 2 * MB);            // 98 ints
    int*   boff     = (int*)  (ws + 2 * MB + 64 * 1024);
    int*   gcursor  = (int*)  (ws + 2 * MB + 128 * 1024);  // 391 ints
    int*   csr      = (int*)  (ws + 3 * MB);            // 6.4 MB
    float* h1s      = (float*)(ws + 10 * MB);           // 25.6 MB
    int2*  tmp      = (int2*) (ws + 10 * MB);           // 12.8 MB, aliases h1s (dead before gemm1)
    float* g1       = (float*)(ws + 36 * MB);           // 25.6 MB
    float* h2s      = (float*)(ws + 62 * MB);           // 12.8 MB

    k_zero   <<<(N_NODES + 255) / 256, 256, 0, stream>>>(udeg);
    k_hist   <<<(N_EDGES + 255) / 256, 256, 0, stream>>>(dst, udeg);
    k_scan_a <<<NB, 256, 0, stream>>>(udeg, dinv, rowstart, bsum);
    k_scan_b <<<1, 128, 0, stream>>>(bsum, boff);
    k_scan_c <<<(N_NODES + 255) / 256, 256, 0, stream>>>(rowstart, boff, cursor);
    k_binit  <<<(NBUCK + 255) / 256, 256, 0, stream>>>(rowstart, gcursor);
    k_bucketA<<<(N_EDGES + 4095) / 4096, 256, 0, stream>>>(src, dst, gcursor, tmp);
    k_bucketB<<<NBUCK, 256, 0, stream>>>(rowstart, tmp, cursor, csr);
    k_gemm1  <<<N_NODES / 16, 256, 0, stream>>>(x, W1, dinv, h1s);
    k_gather1<<<(size_t)N_NODES * 64 / 256, 256, 0, stream>>>(rowstart, udeg, csr, dinv, h1s, b1, g1);
    k_gemm2  <<<N_NODES / 32, 256, 0, stream>>>(g1, W2, dinv, h2s);
    k_gather2<<<(size_t)N_NODES * 32 / 256, 256, 0, stream>>>(rowstart, udeg, csr, dinv, h2s, b2, out);
}